// Round 1
// baseline (393.538 us; speedup 1.0000x reference)
//
#include <hip/hip_runtime.h>
#include <hip/hip_bf16.h>

using short8 = __attribute__((ext_vector_type(8))) short;
using f32x4  = __attribute__((ext_vector_type(4))) float;

constexpr int Bdim = 16;
constexpr int Tdim = 1024;
constexpr int Sdim = 1024;
constexpr int Ddim = 1024;

__device__ __forceinline__ unsigned short f2bfu(float x) {
  unsigned u = __float_as_uint(x);
  u += 0x7fffu + ((u >> 16) & 1u);   // round-to-nearest-even
  return (unsigned short)(u >> 16);
}
__device__ __forceinline__ float bfu2f(unsigned short h) {
  return __uint_as_float((unsigned)h << 16);
}

// ---------- split fp32 -> bf16 (hi, lo) ----------
__global__ void __launch_bounds__(256)
split_kernel(const float* __restrict__ src, unsigned short* __restrict__ hi,
             unsigned short* __restrict__ lo, int n4) {
  int i = blockIdx.x * blockDim.x + threadIdx.x;
  int stride = gridDim.x * blockDim.x;
  for (; i < n4; i += stride) {
    float4 v = reinterpret_cast<const float4*>(src)[i];
    ushort4 h, l;
    h.x = f2bfu(v.x); l.x = f2bfu(v.x - bfu2f(h.x));
    h.y = f2bfu(v.y); l.y = f2bfu(v.y - bfu2f(h.y));
    h.z = f2bfu(v.z); l.z = f2bfu(v.z - bfu2f(h.z));
    h.w = f2bfu(v.w); l.w = f2bfu(v.w - bfu2f(h.w));
    reinterpret_cast<ushort4*>(hi)[i] = h;
    reinterpret_cast<ushort4*>(lo)[i] = l;
  }
}

// ---------- ctx [B,S,D] fp32 -> ctxT [B,D,S] bf16 ----------
__global__ void __launch_bounds__(256)
transpose_ctx_kernel(const float* __restrict__ ctx, unsigned short* __restrict__ ctxT) {
  __shared__ float tile[64][65];
  int b = blockIdx.z;
  int d0 = blockIdx.x * 64, s0 = blockIdx.y * 64;
  const float* src = ctx + (size_t)b * Sdim * Ddim;
  unsigned short* dst = ctxT + (size_t)b * Ddim * Sdim;
  int tx = threadIdx.x & 15, ty = threadIdx.x >> 4;
  #pragma unroll
  for (int r = 0; r < 4; ++r) {
    int s = ty + r * 16;
    float4 v = reinterpret_cast<const float4*>(src + (size_t)(s0 + s) * Ddim + d0)[tx];
    tile[s][tx * 4 + 0] = v.x; tile[s][tx * 4 + 1] = v.y;
    tile[s][tx * 4 + 2] = v.z; tile[s][tx * 4 + 3] = v.w;
  }
  __syncthreads();
  #pragma unroll
  for (int r = 0; r < 4; ++r) {
    int d = ty + r * 16;
    ushort4 o;
    o.x = f2bfu(tile[tx * 4 + 0][d]);
    o.y = f2bfu(tile[tx * 4 + 1][d]);
    o.z = f2bfu(tile[tx * 4 + 2][d]);
    o.w = f2bfu(tile[tx * 4 + 3][d]);
    reinterpret_cast<ushort4*>(dst + (size_t)(d0 + d) * Sdim + s0)[tx] = o;
  }
}

// XOR-swizzled LDS fragment read: logical (row, 8k-granule g) lives at
// phys byte row*64 + (g ^ ((row>>1)&3))*16  (spreads 16 lanes over 8 bank groups)
__device__ __forceinline__ short8 ldsfrag(const unsigned short* s, int rbase, int lane) {
  int row = rbase + (lane & 15);
  int g = (lane >> 4) ^ ((row >> 1) & 3);
  return *reinterpret_cast<const short8*>(s + row * 32 + g * 8);
}

// ---------- B^T-form GEMM: C[m,n] = sum_k A[m,k]*B[n,k], K=N=1024 ----------
// MODE 0: split A,B (3-term MFMA), out -> bf16 hi/lo, row stride 1024
// MODE 1: split A,B, out -> f32 at [(m*16+b)*1024 + n]   ([T,B,N] layout)
// MODE 2: plain bf16, out -> f32 at [(m*16+b)*1024 + n]
template <int MODE>
__global__ void __launch_bounds__(256, 2)
gemm_bt(const unsigned short* __restrict__ Ahi, const unsigned short* __restrict__ Alo,
        const unsigned short* __restrict__ Bhi, const unsigned short* __restrict__ Blo,
        size_t aBatch, size_t bBatch,
        unsigned short* __restrict__ outHi, unsigned short* __restrict__ outLo,
        float* __restrict__ outF) {
  constexpr bool SPLIT = (MODE < 2);
  __shared__ unsigned short sAh[128 * 32];
  __shared__ unsigned short sBh[128 * 32];
  __shared__ unsigned short sAl[SPLIT ? 128 * 32 : 8];
  __shared__ unsigned short sBl[SPLIT ? 128 * 32 : 8];

  const int m0 = blockIdx.x * 128;
  const int n0 = blockIdx.y * 128;
  const int b = blockIdx.z;
  const unsigned short* pAh = Ahi + (size_t)b * aBatch;
  const unsigned short* pBh = Bhi + (size_t)b * bBatch;
  const unsigned short* pAl = SPLIT ? (Alo + (size_t)b * aBatch) : nullptr;
  const unsigned short* pBl = SPLIT ? (Blo + (size_t)b * bBatch) : nullptr;

  const int tid = threadIdx.x;
  const int lane = tid & 63;
  const int wid = tid >> 6;
  const int wr = (wid >> 1) * 64;
  const int wc = (wid & 1) * 64;

  // staging: tile is 128 rows x 32 bf16 (64 B/row); phys byte P -> logical
  // L = P ^ (((P>>7)&3)<<4). Linear LDS dest (global_load_lds requirement),
  // swizzle applied by permuting the per-lane GLOBAL source (m173 pattern).
  int rowS[2], colS[2], ldsOff[2];
  #pragma unroll
  for (int r = 0; r < 2; ++r) {
    int P = tid * 16 + r * 4096;
    int row = P >> 6;
    int L = P ^ (((row >> 1) & 3) << 4);
    rowS[r] = row;
    colS[r] = (L >> 1) & 31;
    ldsOff[r] = wid * 512 + r * 2048;  // wave-uniform LDS base (ushort units)
  }

  f32x4 acc[4][4];
  const f32x4 vzero = {0.f, 0.f, 0.f, 0.f};
  #pragma unroll
  for (int i = 0; i < 4; ++i)
    #pragma unroll
    for (int j = 0; j < 4; ++j) acc[i][j] = vzero;

  #pragma unroll 1
  for (int kt = 0; kt < 1024; kt += 32) {
    #pragma unroll
    for (int r = 0; r < 2; ++r) {
      const unsigned short* gA = pAh + (size_t)(m0 + rowS[r]) * 1024 + kt + colS[r];
      const unsigned short* gB = pBh + (size_t)(n0 + rowS[r]) * 1024 + kt + colS[r];
      __builtin_amdgcn_global_load_lds((const __attribute__((address_space(1))) void*)gA,
                                       (__attribute__((address_space(3))) void*)(sAh + ldsOff[r]),
                                       16, 0, 0);
      __builtin_amdgcn_global_load_lds((const __attribute__((address_space(1))) void*)gB,
                                       (__attribute__((address_space(3))) void*)(sBh + ldsOff[r]),
                                       16, 0, 0);
      if constexpr (SPLIT) {
        const unsigned short* gAl = pAl + (size_t)(m0 + rowS[r]) * 1024 + kt + colS[r];
        const unsigned short* gBl = pBl + (size_t)(n0 + rowS[r]) * 1024 + kt + colS[r];
        __builtin_amdgcn_global_load_lds((const __attribute__((address_space(1))) void*)gAl,
                                         (__attribute__((address_space(3))) void*)(sAl + ldsOff[r]),
                                         16, 0, 0);
        __builtin_amdgcn_global_load_lds((const __attribute__((address_space(1))) void*)gBl,
                                         (__attribute__((address_space(3))) void*)(sBl + ldsOff[r]),
                                         16, 0, 0);
      }
    }
    __syncthreads();

    short8 ah[4], bh[4];
    #pragma unroll
    for (int i = 0; i < 4; ++i) {
      ah[i] = ldsfrag(sAh, wr + i * 16, lane);
      bh[i] = ldsfrag(sBh, wc + i * 16, lane);
    }
    if constexpr (SPLIT) {
      short8 al[4], bl[4];
      #pragma unroll
      for (int i = 0; i < 4; ++i) {
        al[i] = ldsfrag(sAl, wr + i * 16, lane);
        bl[i] = ldsfrag(sBl, wc + i * 16, lane);
      }
      #pragma unroll
      for (int i = 0; i < 4; ++i)
        #pragma unroll
        for (int j = 0; j < 4; ++j) {
          acc[i][j] = __builtin_amdgcn_mfma_f32_16x16x32_bf16(ah[i], bh[j], acc[i][j], 0, 0, 0);
          acc[i][j] = __builtin_amdgcn_mfma_f32_16x16x32_bf16(ah[i], bl[j], acc[i][j], 0, 0, 0);
          acc[i][j] = __builtin_amdgcn_mfma_f32_16x16x32_bf16(al[i], bh[j], acc[i][j], 0, 0, 0);
        }
    } else {
      #pragma unroll
      for (int i = 0; i < 4; ++i)
        #pragma unroll
        for (int j = 0; j < 4; ++j)
          acc[i][j] = __builtin_amdgcn_mfma_f32_16x16x32_bf16(ah[i], bh[j], acc[i][j], 0, 0, 0);
    }
    __syncthreads();
  }

  // C/D layout: col = lane&15, row = (lane>>4)*4 + q  (m89/m91 verified)
  const int lr = (lane >> 4) * 4;
  const int lc = lane & 15;
  #pragma unroll
  for (int i = 0; i < 4; ++i)
    #pragma unroll
    for (int j = 0; j < 4; ++j)
      #pragma unroll
      for (int q = 0; q < 4; ++q) {
        int rr = m0 + wr + i * 16 + lr + q;
        int cc = n0 + wc + j * 16 + lc;
        float v = acc[i][j][q];
        if constexpr (MODE == 0) {
          unsigned short h = f2bfu(v);
          unsigned short l = f2bfu(v - bfu2f(h));
          outHi[(size_t)rr * 1024 + cc] = h;
          outLo[(size_t)rr * 1024 + cc] = l;
        } else {
          outF[((size_t)rr * 16 + b) * 1024 + cc] = v;
        }
      }
}

// ---------- in-place row softmax on [T,B,S] fp32 + bf16 copy to p[B,T,S] ----------
__global__ void __launch_bounds__(256)
softmax_kernel(float* __restrict__ av, unsigned short* __restrict__ p) {
  int row = blockIdx.x;           // row = t*16 + b
  int t = row >> 4, b = row & 15;
  float* a = av + (size_t)row * 1024;
  int tid = threadIdx.x, lane = tid & 63, wid = tid >> 6;
  float4 v = reinterpret_cast<float4*>(a)[tid];
  float mx = fmaxf(fmaxf(v.x, v.y), fmaxf(v.z, v.w));
  #pragma unroll
  for (int o = 1; o < 64; o <<= 1) mx = fmaxf(mx, __shfl_xor(mx, o));
  __shared__ float redM[4], redS[4];
  if (lane == 0) redM[wid] = mx;
  __syncthreads();
  mx = fmaxf(fmaxf(redM[0], redM[1]), fmaxf(redM[2], redM[3]));
  float e0 = __expf(v.x - mx), e1 = __expf(v.y - mx);
  float e2 = __expf(v.z - mx), e3 = __expf(v.w - mx);
  float s = (e0 + e1) + (e2 + e3);
  #pragma unroll
  for (int o = 1; o < 64; o <<= 1) s += __shfl_xor(s, o);
  if (lane == 0) redS[wid] = s;
  __syncthreads();
  s = (redS[0] + redS[1]) + (redS[2] + redS[3]);
  float inv = 1.0f / s;
  float4 o4;
  o4.x = e0 * inv; o4.y = e1 * inv; o4.z = e2 * inv; o4.w = e3 * inv;
  reinterpret_cast<float4*>(a)[tid] = o4;
  ushort4 pb;
  pb.x = f2bfu(o4.x); pb.y = f2bfu(o4.y); pb.z = f2bfu(o4.z); pb.w = f2bfu(o4.w);
  reinterpret_cast<ushort4*>(p + ((size_t)b * Tdim + t) * Sdim)[tid] = pb;
}

extern "C" void kernel_launch(void* const* d_in, const int* in_sizes, int n_in,
                              void* d_out, int out_size, void* d_ws, size_t ws_size,
                              hipStream_t stream) {
  const float* input = (const float*)d_in[0];  // [B,T,D]
  const float* ctx   = (const float*)d_in[1];  // [B,S,D]
  const float* Wt    = (const float*)d_in[2];  // [D,D]
  float* attn_out  = (float*)d_out;                               // [T,B,D]
  float* align_out = attn_out + (size_t)Tdim * Bdim * Ddim;       // [T,B,S]

  const size_t NE = (size_t)Bdim * Tdim * Ddim;  // 16M elems
  // ws regions (132 MB total), serially reused:
  //  A0/A1: input hi/lo  -> (after K1) ctx hi/lo
  //  Whi/Wlo: W split
  //  C0/C1: h hi/lo      -> (after K2) p / ctxT
  unsigned short* A0  = (unsigned short*)d_ws;
  unsigned short* A1  = A0 + NE;
  unsigned short* Whi = A1 + NE;
  unsigned short* Wlo = Whi + (size_t)Ddim * Ddim;
  unsigned short* C0  = Wlo + (size_t)Ddim * Ddim;
  unsigned short* C1  = C0 + NE;

  // split input and W
  split_kernel<<<2048, 256, 0, stream>>>(input, A0, A1, (int)(NE / 4));
  split_kernel<<<512, 256, 0, stream>>>(Wt, Whi, Wlo, (int)((size_t)Ddim * Ddim / 4));
  // K1: h = x @ W^T  (split, bf16 hi/lo out), M = B*T
  gemm_bt<0><<<dim3(Bdim * Tdim / 128, 8, 1), 256, 0, stream>>>(
      A0, A1, Whi, Wlo, 0, 0, C0, C1, nullptr);
  // split ctx (reuse A region)
  split_kernel<<<2048, 256, 0, stream>>>(ctx, A0, A1, (int)(NE / 4));
  // K2: align = h @ ctx^T (split), written straight into d_out region 2 at [T,B,S]
  gemm_bt<1><<<dim3(Tdim / 128, 8, Bdim), 256, 0, stream>>>(
      C0, C1, A0, A1, (size_t)Tdim * Ddim, (size_t)Sdim * Ddim, nullptr, nullptr, align_out);
  // K3: in-place softmax; also emit p bf16 [B,T,S] into C0
  softmax_kernel<<<Bdim * Tdim, 256, 0, stream>>>(align_out, C0);
  // ctxT bf16 [B,D,S] into C1
  transpose_ctx_kernel<<<dim3(16, 16, Bdim), 256, 0, stream>>>(ctx, C1);
  // K4: attn = p @ ctx (plain bf16), out [T,B,D]
  gemm_bt<2><<<dim3(Tdim / 128, 8, Bdim), 256, 0, stream>>>(
      C0, nullptr, C1, nullptr, (size_t)Tdim * Sdim, (size_t)Ddim * Sdim,
      nullptr, nullptr, attn_out);
}

// Round 2
// 317.972 us; speedup vs baseline: 1.2377x; 1.2377x over previous
//
#include <hip/hip_runtime.h>
#include <hip/hip_bf16.h>

using short8 = __attribute__((ext_vector_type(8))) short;
using f32x4  = __attribute__((ext_vector_type(4))) float;

constexpr int Bdim = 16;
constexpr int Tdim = 1024;
constexpr int Sdim = 1024;
constexpr int Ddim = 1024;

__device__ __forceinline__ unsigned short f2bfu(float x) {
  unsigned u = __float_as_uint(x);
  u += 0x7fffu + ((u >> 16) & 1u);   // round-to-nearest-even
  return (unsigned short)(u >> 16);
}
__device__ __forceinline__ float bfu2f(unsigned short h) {
  return __uint_as_float((unsigned)h << 16);
}

// ---------- split fp32 -> bf16 (hi, lo) ----------
__global__ void __launch_bounds__(256)
split_kernel(const float* __restrict__ src, unsigned short* __restrict__ hi,
             unsigned short* __restrict__ lo, int n4) {
  int i = blockIdx.x * blockDim.x + threadIdx.x;
  int stride = gridDim.x * blockDim.x;
  for (; i < n4; i += stride) {
    float4 v = reinterpret_cast<const float4*>(src)[i];
    ushort4 h, l;
    h.x = f2bfu(v.x); l.x = f2bfu(v.x - bfu2f(h.x));
    h.y = f2bfu(v.y); l.y = f2bfu(v.y - bfu2f(h.y));
    h.z = f2bfu(v.z); l.z = f2bfu(v.z - bfu2f(h.z));
    h.w = f2bfu(v.w); l.w = f2bfu(v.w - bfu2f(h.w));
    reinterpret_cast<ushort4*>(hi)[i] = h;
    reinterpret_cast<ushort4*>(lo)[i] = l;
  }
}

// ---------- ctx [B,S,D] fp32 -> ctxT [B,D,S] bf16 ----------
__global__ void __launch_bounds__(256)
transpose_ctx_kernel(const float* __restrict__ ctx, unsigned short* __restrict__ ctxT) {
  __shared__ float tile[64][65];
  int b = blockIdx.z;
  int d0 = blockIdx.x * 64, s0 = blockIdx.y * 64;
  const float* src = ctx + (size_t)b * Sdim * Ddim;
  unsigned short* dst = ctxT + (size_t)b * Ddim * Sdim;
  int tx = threadIdx.x & 15, ty = threadIdx.x >> 4;
  #pragma unroll
  for (int r = 0; r < 4; ++r) {
    int s = ty + r * 16;
    float4 v = reinterpret_cast<const float4*>(src + (size_t)(s0 + s) * Ddim + d0)[tx];
    tile[s][tx * 4 + 0] = v.x; tile[s][tx * 4 + 1] = v.y;
    tile[s][tx * 4 + 2] = v.z; tile[s][tx * 4 + 3] = v.w;
  }
  __syncthreads();
  #pragma unroll
  for (int r = 0; r < 4; ++r) {
    int d = ty + r * 16;
    ushort4 o;
    o.x = f2bfu(tile[tx * 4 + 0][d]);
    o.y = f2bfu(tile[tx * 4 + 1][d]);
    o.z = f2bfu(tile[tx * 4 + 2][d]);
    o.w = f2bfu(tile[tx * 4 + 3][d]);
    reinterpret_cast<ushort4*>(dst + (size_t)(d0 + d) * Sdim + s0)[tx] = o;
  }
}

// XOR-swizzled LDS fragment read (verified 0 bank conflicts in r1):
// logical granule g0 of row lives at phys granule g0 ^ ((row>>1)&3)
__device__ __forceinline__ short8 fragr(const unsigned short* t, int row, int g0) {
  int g = g0 ^ ((row >> 1) & 3);
  return *reinterpret_cast<const short8*>(t + row * 32 + g * 8);
}

#define MFMA1(d, x, y) d = __builtin_amdgcn_mfma_f32_16x16x32_bf16((x), (y), (d), 0, 0, 0)

// ---------- 256x256-tile, BK=32, 8-wave, 4-phase counted-vmcnt GEMM ----------
// C[m,n] = sum_k A[m,k]*B[n,k], K = 1024 (B^T form).
// MODE 0: split A,B (3-term), out bf16 hi/lo at rr*1024+cc
// MODE 1: split A,B, out f32 at (rr*16+b)*1024+cc   ([T,B,N])
// MODE 2: plain bf16,  out f32 at (rr*16+b)*1024+cc
template <int MODE>
__global__ void __launch_bounds__(512, 2)
gemm8(const unsigned short* __restrict__ Ahi, const unsigned short* __restrict__ Alo,
      const unsigned short* __restrict__ Bhi, const unsigned short* __restrict__ Blo,
      size_t aBatch, size_t bBatch,
      unsigned short* __restrict__ outHi, unsigned short* __restrict__ outLo,
      float* __restrict__ outF) {
  constexpr bool SPLIT = (MODE < 2);
  constexpr int NOPS = SPLIT ? 4 : 2;          // {Ah,Al,Bh,Bl} or {Ah,Bh}
  __shared__ unsigned short lds[2 * NOPS * 8192];  // [buf][op][256*32]

  const int m0 = blockIdx.x * 256;
  const int n0 = blockIdx.y * 256;
  const int b  = blockIdx.z;

  const int tid  = threadIdx.x;
  const int lane = tid & 63;
  const int w    = tid >> 6;          // 8 waves: 2(M) x 4(N)
  const int wr   = (w >> 2) * 128;    // wave row base within tile
  const int wc   = (w & 3) * 64;      // wave col base within tile
  const int l15  = lane & 15;
  const int g0   = lane >> 4;

  // staging mapping: thread covers phys 16B granule (srow, tid&3) of a 128-row half;
  // source column pre-swizzled so linear LDS dest == swizzled logical layout (m173)
  const int srow = tid >> 2;                                   // 0..127
  const int scol = ((tid & 3) ^ ((srow >> 1) & 3)) * 8;        // element offset

  const unsigned short* sbase[NOPS];
  {
    const size_t aOff = (size_t)b * aBatch + (size_t)(m0 + srow) * 1024 + scol;
    const size_t bOff = (size_t)b * bBatch + (size_t)(n0 + srow) * 1024 + scol;
    if constexpr (SPLIT) {
      sbase[0] = Ahi + aOff; sbase[1] = Alo + aOff;
      sbase[2] = Bhi + bOff; sbase[3] = Blo + bOff;
    } else {
      sbase[0] = Ahi + aOff; sbase[1] = Bhi + bOff;
    }
  }
  unsigned short* const ldst = lds + tid * 8;

  auto stage = [&](int db, int h, int kt) {
    #pragma unroll
    for (int op = 0; op < NOPS; ++op) {
      const unsigned short* g = sbase[op] + (size_t)h * (128 * 1024) + kt;
      unsigned short* l = ldst + db * (NOPS * 8192) + op * 8192 + h * 4096;
      __builtin_amdgcn_global_load_lds((const __attribute__((address_space(1))) void*)g,
                                       (__attribute__((address_space(3))) void*)l, 16, 0, 0);
    }
  };

  f32x4 acc[8][4];
  const f32x4 vzero = {0.f, 0.f, 0.f, 0.f};
  #pragma unroll
  for (int f = 0; f < 8; ++f)
    #pragma unroll
    for (int j = 0; j < 4; ++j) acc[f][j] = vzero;

  // prologue: stage both halves of buffer 0 (tile k=0); 2*NOPS loads in flight
  stage(0, 0, 0);
  stage(0, 1, 0);

  #pragma unroll 1
  for (int k = 0; k < 32; ++k) {
    const int cur = k & 1;
    const int oth = cur ^ 1;
    const unsigned short* tb  = lds + cur * (NOPS * 8192);
    const unsigned short* tAh = tb;
    const unsigned short* tAl = tb + 8192;
    const unsigned short* tBh = tb + (SPLIT ? 2 : 1) * 8192;
    const unsigned short* tBl = tb + 3 * 8192;
    const int ktn = (k + 1) * 32;

    // ---- P1: prefetch next h0, counted wait for cur buffer, barrier ----
    if (k < 31) {
      stage(oth, 0, ktn);
      asm volatile("" ::: "memory");
      if constexpr (SPLIT) asm volatile("s_waitcnt vmcnt(4)" ::: "memory");
      else                 asm volatile("s_waitcnt vmcnt(2)" ::: "memory");
    } else {
      asm volatile("s_waitcnt vmcnt(0)" ::: "memory");
    }
    __builtin_amdgcn_s_barrier();
    asm volatile("" ::: "memory");

    short8 ah[4], al[4], bh[4], bl[4];
    #pragma unroll
    for (int f = 0; f < 4; ++f) {
      ah[f] = fragr(tAh, wr + f * 16 + l15, g0);
      if constexpr (SPLIT) al[f] = fragr(tAl, wr + f * 16 + l15, g0);
    }
    #pragma unroll
    for (int j = 0; j < 2; ++j) {
      bh[j] = fragr(tBh, wc + j * 16 + l15, g0);
      if constexpr (SPLIT) bl[j] = fragr(tBl, wc + j * 16 + l15, g0);
    }
    __builtin_amdgcn_s_setprio(1);
    #pragma unroll
    for (int f = 0; f < 4; ++f)
      #pragma unroll
      for (int j = 0; j < 2; ++j) {
        MFMA1(acc[f][j], ah[f], bh[j]);
        if constexpr (SPLIT) { MFMA1(acc[f][j], ah[f], bl[j]); MFMA1(acc[f][j], al[f], bh[j]); }
      }
    __builtin_amdgcn_s_setprio(0);

    // ---- P2: N-frags 2..3 with same A-frags ----
    #pragma unroll
    for (int j = 2; j < 4; ++j) {
      bh[j] = fragr(tBh, wc + j * 16 + l15, g0);
      if constexpr (SPLIT) bl[j] = fragr(tBl, wc + j * 16 + l15, g0);
    }
    __builtin_amdgcn_s_setprio(1);
    #pragma unroll
    for (int f = 0; f < 4; ++f)
      #pragma unroll
      for (int j = 2; j < 4; ++j) {
        MFMA1(acc[f][j], ah[f], bh[j]);
        if constexpr (SPLIT) { MFMA1(acc[f][j], ah[f], bl[j]); MFMA1(acc[f][j], al[f], bh[j]); }
      }
    __builtin_amdgcn_s_setprio(0);

    // ---- P3: prefetch next h1, M-frags 4..7, N-frags 0..1 ----
    if (k < 31) stage(oth, 1, ktn);
    #pragma unroll
    for (int f = 0; f < 4; ++f) {
      ah[f] = fragr(tAh, wr + 64 + f * 16 + l15, g0);
      if constexpr (SPLIT) al[f] = fragr(tAl, wr + 64 + f * 16 + l15, g0);
    }
    __builtin_amdgcn_s_setprio(1);
    #pragma unroll
    for (int f = 0; f < 4; ++f)
      #pragma unroll
      for (int j = 0; j < 2; ++j) {
        MFMA1(acc[4 + f][j], ah[f], bh[j]);
        if constexpr (SPLIT) { MFMA1(acc[4 + f][j], ah[f], bl[j]); MFMA1(acc[4 + f][j], al[f], bh[j]); }
      }
    __builtin_amdgcn_s_setprio(0);

    // ---- P4: M-frags 4..7, N-frags 2..3 ----
    __builtin_amdgcn_s_setprio(1);
    #pragma unroll
    for (int f = 0; f < 4; ++f)
      #pragma unroll
      for (int j = 2; j < 4; ++j) {
        MFMA1(acc[4 + f][j], ah[f], bh[j]);
        if constexpr (SPLIT) { MFMA1(acc[4 + f][j], ah[f], bl[j]); MFMA1(acc[4 + f][j], al[f], bh[j]); }
      }
    __builtin_amdgcn_s_setprio(0);
    asm volatile("" ::: "memory");
    __builtin_amdgcn_s_barrier();
  }

  // ---- epilogue: C/D layout col=lane&15, row=(lane>>4)*4+q ----
  const int lr = (lane >> 4) * 4;
  const int lc = lane & 15;
  #pragma unroll
  for (int f = 0; f < 8; ++f)
    #pragma unroll
    for (int j = 0; j < 4; ++j)
      #pragma unroll
      for (int q = 0; q < 4; ++q) {
        int rr = m0 + wr + f * 16 + lr + q;
        int cc = n0 + wc + j * 16 + lc;
        float v = acc[f][j][q];
        if constexpr (MODE == 0) {
          unsigned short h = f2bfu(v);
          unsigned short l = f2bfu(v - bfu2f(h));
          outHi[(size_t)rr * 1024 + cc] = h;
          outLo[(size_t)rr * 1024 + cc] = l;
        } else {
          outF[((size_t)rr * 16 + b) * 1024 + cc] = v;
        }
      }
}

// ---------- in-place row softmax on [T,B,S] fp32 + bf16 copy to p[B,T,S] ----------
__global__ void __launch_bounds__(256)
softmax_kernel(float* __restrict__ av, unsigned short* __restrict__ p) {
  int row = blockIdx.x;           // row = t*16 + b
  int t = row >> 4, b = row & 15;
  float* a = av + (size_t)row * 1024;
  int tid = threadIdx.x, lane = tid & 63, wid = tid >> 6;
  float4 v = reinterpret_cast<float4*>(a)[tid];
  float mx = fmaxf(fmaxf(v.x, v.y), fmaxf(v.z, v.w));
  #pragma unroll
  for (int o = 1; o < 64; o <<= 1) mx = fmaxf(mx, __shfl_xor(mx, o));
  __shared__ float redM[4], redS[4];
  if (lane == 0) redM[wid] = mx;
  __syncthreads();
  mx = fmaxf(fmaxf(redM[0], redM[1]), fmaxf(redM[2], redM[3]));
  float e0 = __expf(v.x - mx), e1 = __expf(v.y - mx);
  float e2 = __expf(v.z - mx), e3 = __expf(v.w - mx);
  float s = (e0 + e1) + (e2 + e3);
  #pragma unroll
  for (int o = 1; o < 64; o <<= 1) s += __shfl_xor(s, o);
  if (lane == 0) redS[wid] = s;
  __syncthreads();
  s = (redS[0] + redS[1]) + (redS[2] + redS[3]);
  float inv = 1.0f / s;
  float4 o4;
  o4.x = e0 * inv; o4.y = e1 * inv; o4.z = e2 * inv; o4.w = e3 * inv;
  reinterpret_cast<float4*>(a)[tid] = o4;
  ushort4 pb;
  pb.x = f2bfu(o4.x); pb.y = f2bfu(o4.y); pb.z = f2bfu(o4.z); pb.w = f2bfu(o4.w);
  reinterpret_cast<ushort4*>(p + ((size_t)b * Tdim + t) * Sdim)[tid] = pb;
}

extern "C" void kernel_launch(void* const* d_in, const int* in_sizes, int n_in,
                              void* d_out, int out_size, void* d_ws, size_t ws_size,
                              hipStream_t stream) {
  const float* input = (const float*)d_in[0];  // [B,T,D]
  const float* ctx   = (const float*)d_in[1];  // [B,S,D]
  const float* Wt    = (const float*)d_in[2];  // [D,D]
  float* attn_out  = (float*)d_out;                               // [T,B,D]
  float* align_out = attn_out + (size_t)Tdim * Bdim * Ddim;       // [T,B,S]

  const size_t NE = (size_t)Bdim * Tdim * Ddim;  // 16M elems
  unsigned short* A0  = (unsigned short*)d_ws;
  unsigned short* A1  = A0 + NE;
  unsigned short* Whi = A1 + NE;
  unsigned short* Wlo = Whi + (size_t)Ddim * Ddim;
  unsigned short* C0  = Wlo + (size_t)Ddim * Ddim;
  unsigned short* C1  = C0 + NE;

  // split input and W
  split_kernel<<<2048, 256, 0, stream>>>(input, A0, A1, (int)(NE / 4));
  split_kernel<<<512, 256, 0, stream>>>(Wt, Whi, Wlo, (int)((size_t)Ddim * Ddim / 4));
  // K1: h = x @ W^T  (split, bf16 hi/lo out), M = B*T = 16384
  gemm8<0><<<dim3(64, 4, 1), 512, 0, stream>>>(
      A0, A1, Whi, Wlo, 0, 0, C0, C1, nullptr);
  // split ctx (reuse A region)
  split_kernel<<<2048, 256, 0, stream>>>(ctx, A0, A1, (int)(NE / 4));
  // K2: align = h @ ctx^T (split), out f32 [T,B,S]
  gemm8<1><<<dim3(4, 4, 16), 512, 0, stream>>>(
      C0, C1, A0, A1, (size_t)Tdim * Ddim, (size_t)Sdim * Ddim, nullptr, nullptr, align_out);
  // K3: in-place softmax; also emit p bf16 [B,T,S] into C0
  softmax_kernel<<<Bdim * Tdim, 256, 0, stream>>>(align_out, C0);
  // ctxT bf16 [B,D,S] into C1
  transpose_ctx_kernel<<<dim3(16, 16, Bdim), 256, 0, stream>>>(ctx, C1);
  // K4: attn = p @ ctx (plain bf16), out [T,B,D]
  gemm8<2><<<dim3(4, 4, 16), 512, 0, stream>>>(
      C0, nullptr, C1, nullptr, (size_t)Tdim * Sdim, (size_t)Ddim * Sdim,
      nullptr, nullptr, attn_out);
}

// Round 3
// 305.858 us; speedup vs baseline: 1.2867x; 1.0396x over previous
//
#include <hip/hip_runtime.h>
#include <hip/hip_bf16.h>

using short8 = __attribute__((ext_vector_type(8))) short;
using f32x4  = __attribute__((ext_vector_type(4))) float;

constexpr int Bdim = 16;
constexpr int Tdim = 1024;
constexpr int Sdim = 1024;
constexpr int Ddim = 1024;

__device__ __forceinline__ unsigned short f2bfu(float x) {
  unsigned u = __float_as_uint(x);
  u += 0x7fffu + ((u >> 16) & 1u);   // round-to-nearest-even
  return (unsigned short)(u >> 16);
}
__device__ __forceinline__ float bfu2f(unsigned short h) {
  return __uint_as_float((unsigned)h << 16);
}

// ---------- split fp32 -> bf16 (hi, lo) ----------
__global__ void __launch_bounds__(256)
split_kernel(const float* __restrict__ src, unsigned short* __restrict__ hi,
             unsigned short* __restrict__ lo, int n4) {
  int i = blockIdx.x * blockDim.x + threadIdx.x;
  int stride = gridDim.x * blockDim.x;
  for (; i < n4; i += stride) {
    float4 v = reinterpret_cast<const float4*>(src)[i];
    ushort4 h, l;
    h.x = f2bfu(v.x); l.x = f2bfu(v.x - bfu2f(h.x));
    h.y = f2bfu(v.y); l.y = f2bfu(v.y - bfu2f(h.y));
    h.z = f2bfu(v.z); l.z = f2bfu(v.z - bfu2f(h.z));
    h.w = f2bfu(v.w); l.w = f2bfu(v.w - bfu2f(h.w));
    reinterpret_cast<ushort4*>(hi)[i] = h;
    reinterpret_cast<ushort4*>(lo)[i] = l;
  }
}

// ---------- ctx [B,S,D] fp32 -> ctxT [B,D,S] bf16 ----------
__global__ void __launch_bounds__(256)
transpose_ctx_kernel(const float* __restrict__ ctx, unsigned short* __restrict__ ctxT) {
  __shared__ float tile[64][65];
  int b = blockIdx.z;
  int d0 = blockIdx.x * 64, s0 = blockIdx.y * 64;
  const float* src = ctx + (size_t)b * Sdim * Ddim;
  unsigned short* dst = ctxT + (size_t)b * Ddim * Sdim;
  int tx = threadIdx.x & 15, ty = threadIdx.x >> 4;
  #pragma unroll
  for (int r = 0; r < 4; ++r) {
    int s = ty + r * 16;
    float4 v = reinterpret_cast<const float4*>(src + (size_t)(s0 + s) * Ddim + d0)[tx];
    tile[s][tx * 4 + 0] = v.x; tile[s][tx * 4 + 1] = v.y;
    tile[s][tx * 4 + 2] = v.z; tile[s][tx * 4 + 3] = v.w;
  }
  __syncthreads();
  #pragma unroll
  for (int r = 0; r < 4; ++r) {
    int d = ty + r * 16;
    ushort4 o;
    o.x = f2bfu(tile[tx * 4 + 0][d]);
    o.y = f2bfu(tile[tx * 4 + 1][d]);
    o.z = f2bfu(tile[tx * 4 + 2][d]);
    o.w = f2bfu(tile[tx * 4 + 3][d]);
    reinterpret_cast<ushort4*>(dst + (size_t)(d0 + d) * Sdim + s0)[tx] = o;
  }
}

// split-mode LDS frag read (BK=32, 64B rows, r2-verified 0 conflicts):
// logical granule g of row at phys granule g ^ ((row>>1)&3)
__device__ __forceinline__ short8 fragr32(const unsigned short* t, int row, int g0) {
  int pg = g0 ^ ((row >> 1) & 3);
  return *reinterpret_cast<const short8*>(t + row * 32 + pg * 8);
}
// plain-mode LDS frag read (BK=64, 128B rows): logical granule (kk*4+g0)
// at phys granule ^ (row&7) — 16 lanes spread over all 8 granules (2-way free)
__device__ __forceinline__ short8 fragr64(const unsigned short* t, int row, int kk, int g0) {
  int pg = (kk * 4 + g0) ^ (row & 7);
  return *reinterpret_cast<const short8*>(t + row * 64 + pg * 8);
}

#define MFMA1(d, x, y) d = __builtin_amdgcn_mfma_f32_16x16x32_bf16((x), (y), (d), 0, 0, 0)

// ---------- 256x256 tile, 8-wave, 4-phase barrier-pair counted-vmcnt GEMM ----------
// C[m,n] = sum_k A[m,k]*B[n,k], K = 1024 (B^T form).
// MODE 0: split A,B (3-term, BK=32), out bf16 hi/lo at rr*1024+cc
// MODE 1: split A,B (BK=32), out f32 at (rr*16+b)*1024+cc   ([T,B,N])
// MODE 2: plain bf16 (BK=64), out f32 at (rr*16+b)*1024+cc
template <int MODE>
__global__ void __launch_bounds__(512, 2)
gemm8(const unsigned short* __restrict__ Ahi, const unsigned short* __restrict__ Alo,
      const unsigned short* __restrict__ Bhi, const unsigned short* __restrict__ Blo,
      size_t aBatch, size_t bBatch, int mnShift,
      unsigned short* __restrict__ outHi, unsigned short* __restrict__ outLo,
      float* __restrict__ outF) {
  constexpr bool SPLIT = (MODE < 2);
  constexpr int NT = SPLIT ? 32 : 16;          // K-tiles (BK = 32 / 64)
  __shared__ __align__(16) unsigned short lds[65536];  // 128 KiB: [buf][ops...]

  // XCD-chunked swizzle: hw round-robins bid%8 -> L contiguous per XCD
  const int hw = blockIdx.x;
  const int L  = (hw & 7) * 32 + (hw >> 3);
  const int bb = L >> mnShift;
  const int r  = L & ((1 << mnShift) - 1);
  const int m0 = (r >> 2) * 256;
  const int n0 = (r & 3) * 256;

  const int tid  = threadIdx.x;
  const int lane = tid & 63;
  const int w    = tid >> 6;          // 8 waves: 2(M) x 4(N)
  const int wr   = (w >> 2) * 128;
  const int wc   = (w & 3) * 64;
  const int l15  = lane & 15;
  const int g0   = lane >> 4;

  // staging source pointers (pre-swizzled global col per m173)
  const unsigned short* sp[SPLIT ? 4 : 2];
  if constexpr (SPLIT) {
    const int srow = tid >> 2;
    const int scol = ((tid & 3) ^ ((srow >> 1) & 3)) * 8;
    const size_t aOff = (size_t)bb * aBatch + (size_t)(m0 + srow) * 1024 + scol;
    const size_t bOff = (size_t)bb * bBatch + (size_t)(n0 + srow) * 1024 + scol;
    sp[0] = Ahi + aOff; sp[1] = Alo + aOff;
    sp[2] = Bhi + bOff; sp[3] = Blo + bOff;
  } else {
    const int srow = tid >> 3;
    const int scol = ((tid & 7) ^ (srow & 7)) * 8;
    sp[0] = Ahi + (size_t)bb * aBatch + (size_t)(m0 + srow) * 1024 + scol;
    sp[1] = Bhi + (size_t)bb * bBatch + (size_t)(n0 + srow) * 1024 + scol;
  }

  // stage one 128-row half of tile `kt` into buf: always 4 load instrs/wave
  auto stage_half = [&](int buf, int h, int kt) {
    if constexpr (SPLIT) {
      #pragma unroll
      for (int op = 0; op < 4; ++op) {
        const unsigned short* g = sp[op] + (size_t)h * (128 * 1024) + kt * 32;
        unsigned short* l = lds + buf * 32768 + op * 8192 + h * 4096 + tid * 8;
        __builtin_amdgcn_global_load_lds((const __attribute__((address_space(1))) void*)g,
                                         (__attribute__((address_space(3))) void*)l, 16, 0, 0);
      }
    } else {
      #pragma unroll
      for (int op = 0; op < 2; ++op)
        #pragma unroll
        for (int s = 0; s < 2; ++s) {
          const unsigned short* g = sp[op] + (size_t)(h * 128 + s * 64) * 1024 + kt * 64;
          unsigned short* l = lds + buf * 32768 + op * 16384 + h * 8192 + s * 4096 + tid * 8;
          __builtin_amdgcn_global_load_lds((const __attribute__((address_space(1))) void*)g,
                                           (__attribute__((address_space(3))) void*)l, 16, 0, 0);
        }
    }
  };

  f32x4 acc[8][4];
  const f32x4 vzero = {0.f, 0.f, 0.f, 0.f};
  #pragma unroll
  for (int f = 0; f < 8; ++f)
    #pragma unroll
    for (int j = 0; j < 4; ++j) acc[f][j] = vzero;

  short8 ah[4], al[4], bh0[2], bl0[2], bh1[2], bl1[2];     // split regs
  short8 pa[4][2], pb0[2][2], pb1[2][2];                   // plain regs

  // prologue: tile0 both halves + tile1 h0; drain tile0 (keep 4 in flight)
  stage_half(0, 0, 0);
  stage_half(0, 1, 0);
  stage_half(1, 0, 1);
  asm volatile("s_waitcnt vmcnt(4)" ::: "memory");
  __builtin_amdgcn_s_barrier();

  #pragma unroll 1
  for (int t = 0; t < NT; ++t) {
    const int c = t & 1;
    const unsigned short* tb = lds + c * 32768;

    // ======== q0: frags {f0-3 x j0-1}; stage h1 of t+1 ========
    if constexpr (SPLIT) {
      #pragma unroll
      for (int f = 0; f < 4; ++f) {
        ah[f] = fragr32(tb,        wr + f * 16 + l15, g0);
        al[f] = fragr32(tb + 8192, wr + f * 16 + l15, g0);
      }
      #pragma unroll
      for (int j = 0; j < 2; ++j) {
        bh0[j] = fragr32(tb + 16384, wc + j * 16 + l15, g0);
        bl0[j] = fragr32(tb + 24576, wc + j * 16 + l15, g0);
      }
    } else {
      #pragma unroll
      for (int f = 0; f < 4; ++f)
        #pragma unroll
        for (int kk = 0; kk < 2; ++kk)
          pa[f][kk] = fragr64(tb, wr + f * 16 + l15, kk, g0);
      #pragma unroll
      for (int j = 0; j < 2; ++j)
        #pragma unroll
        for (int kk = 0; kk < 2; ++kk)
          pb0[j][kk] = fragr64(tb + 16384, wc + j * 16 + l15, kk, g0);
    }
    if (t + 1 < NT) stage_half(c ^ 1, 1, t + 1);
    __builtin_amdgcn_s_barrier();
    asm volatile("s_waitcnt lgkmcnt(0)" ::: "memory");
    __builtin_amdgcn_sched_barrier(0);
    __builtin_amdgcn_s_setprio(1);
    #pragma unroll
    for (int f = 0; f < 4; ++f)
      #pragma unroll
      for (int j = 0; j < 2; ++j) {
        if constexpr (SPLIT) {
          MFMA1(acc[f][j], ah[f], bh0[j]);
          MFMA1(acc[f][j], ah[f], bl0[j]);
          MFMA1(acc[f][j], al[f], bh0[j]);
        } else {
          MFMA1(acc[f][j], pa[f][0], pb0[j][0]);
          MFMA1(acc[f][j], pa[f][1], pb0[j][1]);
        }
      }
    __builtin_amdgcn_s_setprio(0);
    __builtin_amdgcn_s_barrier();

    // ======== q1: frags {f0-3 x j2-3} ========
    if constexpr (SPLIT) {
      #pragma unroll
      for (int j = 0; j < 2; ++j) {
        bh1[j] = fragr32(tb + 16384, wc + (j + 2) * 16 + l15, g0);
        bl1[j] = fragr32(tb + 24576, wc + (j + 2) * 16 + l15, g0);
      }
    } else {
      #pragma unroll
      for (int j = 0; j < 2; ++j)
        #pragma unroll
        for (int kk = 0; kk < 2; ++kk)
          pb1[j][kk] = fragr64(tb + 16384, wc + (j + 2) * 16 + l15, kk, g0);
    }
    __builtin_amdgcn_s_barrier();
    asm volatile("s_waitcnt lgkmcnt(0)" ::: "memory");
    __builtin_amdgcn_sched_barrier(0);
    __builtin_amdgcn_s_setprio(1);
    #pragma unroll
    for (int f = 0; f < 4; ++f)
      #pragma unroll
      for (int j = 0; j < 2; ++j) {
        if constexpr (SPLIT) {
          MFMA1(acc[f][j + 2], ah[f], bh1[j]);
          MFMA1(acc[f][j + 2], ah[f], bl1[j]);
          MFMA1(acc[f][j + 2], al[f], bh1[j]);
        } else {
          MFMA1(acc[f][j + 2], pa[f][0], pb1[j][0]);
          MFMA1(acc[f][j + 2], pa[f][1], pb1[j][1]);
        }
      }
    __builtin_amdgcn_s_setprio(0);
    __builtin_amdgcn_s_barrier();

    // ======== q2: frags {f4-7 x j0-1} (re-read A regs) ========
    if constexpr (SPLIT) {
      #pragma unroll
      for (int f = 0; f < 4; ++f) {
        ah[f] = fragr32(tb,        wr + 64 + f * 16 + l15, g0);
        al[f] = fragr32(tb + 8192, wr + 64 + f * 16 + l15, g0);
      }
    } else {
      #pragma unroll
      for (int f = 0; f < 4; ++f)
        #pragma unroll
        for (int kk = 0; kk < 2; ++kk)
          pa[f][kk] = fragr64(tb, wr + 64 + f * 16 + l15, kk, g0);
    }
    __builtin_amdgcn_s_barrier();
    asm volatile("s_waitcnt lgkmcnt(0)" ::: "memory");
    __builtin_amdgcn_sched_barrier(0);
    __builtin_amdgcn_s_setprio(1);
    #pragma unroll
    for (int f = 0; f < 4; ++f)
      #pragma unroll
      for (int j = 0; j < 2; ++j) {
        if constexpr (SPLIT) {
          MFMA1(acc[4 + f][j], ah[f], bh0[j]);
          MFMA1(acc[4 + f][j], ah[f], bl0[j]);
          MFMA1(acc[4 + f][j], al[f], bh0[j]);
        } else {
          MFMA1(acc[4 + f][j], pa[f][0], pb0[j][0]);
          MFMA1(acc[4 + f][j], pa[f][1], pb0[j][1]);
        }
      }
    __builtin_amdgcn_s_setprio(0);
    __builtin_amdgcn_s_barrier();

    // ======== q3: frags {f4-7 x j2-3}; stage h0 of t+2; counted vmcnt ========
    if (t + 2 < NT) stage_half(c, 0, t + 2);
    __builtin_amdgcn_s_barrier();
    __builtin_amdgcn_sched_barrier(0);
    __builtin_amdgcn_s_setprio(1);
    #pragma unroll
    for (int f = 0; f < 4; ++f)
      #pragma unroll
      for (int j = 0; j < 2; ++j) {
        if constexpr (SPLIT) {
          MFMA1(acc[4 + f][j + 2], ah[f], bh1[j]);
          MFMA1(acc[4 + f][j + 2], ah[f], bl1[j]);
          MFMA1(acc[4 + f][j + 2], al[f], bh1[j]);
        } else {
          MFMA1(acc[4 + f][j + 2], pa[f][0], pb1[j][0]);
          MFMA1(acc[4 + f][j + 2], pa[f][1], pb1[j][1]);
        }
      }
    __builtin_amdgcn_s_setprio(0);
    if (t + 2 < NT) asm volatile("s_waitcnt vmcnt(4)" ::: "memory");
    else            asm volatile("s_waitcnt vmcnt(0)" ::: "memory");
    __builtin_amdgcn_s_barrier();
  }

  // ---- epilogue: C/D layout col=lane&15, row=(lane>>4)*4+q ----
  const int lr = (lane >> 4) * 4;
  const int lc = lane & 15;
  #pragma unroll
  for (int f = 0; f < 8; ++f)
    #pragma unroll
    for (int j = 0; j < 4; ++j)
      #pragma unroll
      for (int q = 0; q < 4; ++q) {
        int rr = m0 + wr + f * 16 + lr + q;
        int cc = n0 + wc + j * 16 + lc;
        float v = acc[f][j][q];
        if constexpr (MODE == 0) {
          unsigned short h = f2bfu(v);
          unsigned short l = f2bfu(v - bfu2f(h));
          outHi[(size_t)rr * 1024 + cc] = h;
          outLo[(size_t)rr * 1024 + cc] = l;
        } else {
          outF[((size_t)rr * 16 + bb) * 1024 + cc] = v;
        }
      }
}

// ---------- in-place row softmax on [T,B,S] fp32 + bf16 copy to p[B,T,S] ----------
__global__ void __launch_bounds__(256)
softmax_kernel(float* __restrict__ av, unsigned short* __restrict__ p) {
  int row = blockIdx.x;           // row = t*16 + b
  int t = row >> 4, b = row & 15;
  float* a = av + (size_t)row * 1024;
  int tid = threadIdx.x, lane = tid & 63, wid = tid >> 6;
  float4 v = reinterpret_cast<float4*>(a)[tid];
  float mx = fmaxf(fmaxf(v.x, v.y), fmaxf(v.z, v.w));
  #pragma unroll
  for (int o = 1; o < 64; o <<= 1) mx = fmaxf(mx, __shfl_xor(mx, o));
  __shared__ float redM[4], redS[4];
  if (lane == 0) redM[wid] = mx;
  __syncthreads();
  mx = fmaxf(fmaxf(redM[0], redM[1]), fmaxf(redM[2], redM[3]));
  float e0 = __expf(v.x - mx), e1 = __expf(v.y - mx);
  float e2 = __expf(v.z - mx), e3 = __expf(v.w - mx);
  float s = (e0 + e1) + (e2 + e3);
  #pragma unroll
  for (int o = 1; o < 64; o <<= 1) s += __shfl_xor(s, o);
  if (lane == 0) redS[wid] = s;
  __syncthreads();
  s = (redS[0] + redS[1]) + (redS[2] + redS[3]);
  float inv = 1.0f / s;
  float4 o4;
  o4.x = e0 * inv; o4.y = e1 * inv; o4.z = e2 * inv; o4.w = e3 * inv;
  reinterpret_cast<float4*>(a)[tid] = o4;
  ushort4 pb;
  pb.x = f2bfu(o4.x); pb.y = f2bfu(o4.y); pb.z = f2bfu(o4.z); pb.w = f2bfu(o4.w);
  reinterpret_cast<ushort4*>(p + ((size_t)b * Tdim + t) * Sdim)[tid] = pb;
}

extern "C" void kernel_launch(void* const* d_in, const int* in_sizes, int n_in,
                              void* d_out, int out_size, void* d_ws, size_t ws_size,
                              hipStream_t stream) {
  const float* input = (const float*)d_in[0];  // [B,T,D]
  const float* ctx   = (const float*)d_in[1];  // [B,S,D]
  const float* Wt    = (const float*)d_in[2];  // [D,D]
  float* attn_out  = (float*)d_out;                               // [T,B,D]
  float* align_out = attn_out + (size_t)Tdim * Bdim * Ddim;       // [T,B,S]

  const size_t NE = (size_t)Bdim * Tdim * Ddim;  // 16M elems
  unsigned short* A0  = (unsigned short*)d_ws;
  unsigned short* A1  = A0 + NE;
  unsigned short* Whi = A1 + NE;
  unsigned short* Wlo = Whi + (size_t)Ddim * Ddim;
  unsigned short* C0  = Wlo + (size_t)Ddim * Ddim;
  unsigned short* C1  = C0 + NE;

  // split input and W
  split_kernel<<<2048, 256, 0, stream>>>(input, A0, A1, (int)(NE / 4));
  split_kernel<<<512, 256, 0, stream>>>(Wt, Whi, Wlo, (int)((size_t)Ddim * Ddim / 4));
  // K1: h = x @ W^T (split), M = 16384 -> 64x4 tiles, mnShift=8
  gemm8<0><<<256, 512, 0, stream>>>(
      A0, A1, Whi, Wlo, 0, 0, 8, C0, C1, nullptr);
  // split ctx (reuse A region)
  split_kernel<<<2048, 256, 0, stream>>>(ctx, A0, A1, (int)(NE / 4));
  // K2: align = h @ ctx^T (split), 16 batches x 4x4 tiles, mnShift=4
  gemm8<1><<<256, 512, 0, stream>>>(
      C0, C1, A0, A1, (size_t)Tdim * Ddim, (size_t)Sdim * Ddim, 4, nullptr, nullptr, align_out);
  // K3: in-place softmax; also emit p bf16 [B,T,S] into C0
  softmax_kernel<<<Bdim * Tdim, 256, 0, stream>>>(align_out, C0);
  // ctxT bf16 [B,D,S] into C1
  transpose_ctx_kernel<<<dim3(16, 16, Bdim), 256, 0, stream>>>(ctx, C1);
  // K4: attn = p @ ctx (plain bf16, BK=64), out [T,B,D]
  gemm8<2><<<256, 512, 0, stream>>>(
      C0, nullptr, C1, nullptr, (size_t)Tdim * Sdim, (size_t)Ddim * Sdim, 4,
      nullptr, nullptr, attn_out);
}

// Round 4
// 305.765 us; speedup vs baseline: 1.2871x; 1.0003x over previous
//
#include <hip/hip_runtime.h>
#include <hip/hip_bf16.h>

using short8 = __attribute__((ext_vector_type(8))) short;
using f32x4  = __attribute__((ext_vector_type(4))) float;

constexpr int Bdim = 16;
constexpr int Tdim = 1024;
constexpr int Sdim = 1024;
constexpr int Ddim = 1024;

__device__ __forceinline__ unsigned short f2bfu(float x) {
  unsigned u = __float_as_uint(x);
  u += 0x7fffu + ((u >> 16) & 1u);   // round-to-nearest-even
  return (unsigned short)(u >> 16);
}
__device__ __forceinline__ float bfu2f(unsigned short h) {
  return __uint_as_float((unsigned)h << 16);
}

// ---------- split fp32 -> bf16 (hi, lo) ----------
__global__ void __launch_bounds__(256)
split_kernel(const float* __restrict__ src, unsigned short* __restrict__ hi,
             unsigned short* __restrict__ lo, int n4) {
  int i = blockIdx.x * blockDim.x + threadIdx.x;
  int stride = gridDim.x * blockDim.x;
  for (; i < n4; i += stride) {
    float4 v = reinterpret_cast<const float4*>(src)[i];
    ushort4 h, l;
    h.x = f2bfu(v.x); l.x = f2bfu(v.x - bfu2f(h.x));
    h.y = f2bfu(v.y); l.y = f2bfu(v.y - bfu2f(h.y));
    h.z = f2bfu(v.z); l.z = f2bfu(v.z - bfu2f(h.z));
    h.w = f2bfu(v.w); l.w = f2bfu(v.w - bfu2f(h.w));
    reinterpret_cast<ushort4*>(hi)[i] = h;
    reinterpret_cast<ushort4*>(lo)[i] = l;
  }
}

// ---------- ctx [B,S,D] fp32 -> ctxT [B,D,S] bf16 ----------
__global__ void __launch_bounds__(256)
transpose_ctx_kernel(const float* __restrict__ ctx, unsigned short* __restrict__ ctxT) {
  __shared__ float tile[64][65];
  int b = blockIdx.z;
  int d0 = blockIdx.x * 64, s0 = blockIdx.y * 64;
  const float* src = ctx + (size_t)b * Sdim * Ddim;
  unsigned short* dst = ctxT + (size_t)b * Ddim * Sdim;
  int tx = threadIdx.x & 15, ty = threadIdx.x >> 4;
  #pragma unroll
  for (int r = 0; r < 4; ++r) {
    int s = ty + r * 16;
    float4 v = reinterpret_cast<const float4*>(src + (size_t)(s0 + s) * Ddim + d0)[tx];
    tile[s][tx * 4 + 0] = v.x; tile[s][tx * 4 + 1] = v.y;
    tile[s][tx * 4 + 2] = v.z; tile[s][tx * 4 + 3] = v.w;
  }
  __syncthreads();
  #pragma unroll
  for (int r = 0; r < 4; ++r) {
    int d = ty + r * 16;
    ushort4 o;
    o.x = f2bfu(tile[tx * 4 + 0][d]);
    o.y = f2bfu(tile[tx * 4 + 1][d]);
    o.z = f2bfu(tile[tx * 4 + 2][d]);
    o.w = f2bfu(tile[tx * 4 + 3][d]);
    reinterpret_cast<ushort4*>(dst + (size_t)(d0 + d) * Sdim + s0)[tx] = o;
  }
}

// LDS frag read, 64B rows (r1-verified 0 conflicts):
// logical granule g of row at phys granule g ^ ((row>>1)&3)
__device__ __forceinline__ short8 fragr32(const unsigned short* t, int row, int g0) {
  int pg = g0 ^ ((row >> 1) & 3);
  return *reinterpret_cast<const short8*>(t + row * 32 + pg * 8);
}

#define MFMA1(d, x, y) d = __builtin_amdgcn_mfma_f32_16x16x32_bf16((x), (y), (d), 0, 0, 0)

// ---------- 256x256 tile, 8-wave, split (3-term) GEMM ----------
// C[m,n] = sum_k A[m,k]*B[n,k], K = 1024 (B^T form).
// MODE 0: out bf16 hi/lo at rr*1024+cc
// MODE 1: out f32 at (rr*16+b)*1024+cc   ([T,B,N])
template <int MODE>
__global__ void __launch_bounds__(512, 2)
gemm8(const unsigned short* __restrict__ Ahi, const unsigned short* __restrict__ Alo,
      const unsigned short* __restrict__ Bhi, const unsigned short* __restrict__ Blo,
      size_t aBatch, size_t bBatch, int mnShift,
      unsigned short* __restrict__ outHi, unsigned short* __restrict__ outLo,
      float* __restrict__ outF) {
  constexpr int NT = 32;          // K-tiles (BK = 32)
  __shared__ __align__(16) unsigned short lds[65536];  // 128 KiB

  const int hw = blockIdx.x;
  const int L  = (hw & 7) * 32 + (hw >> 3);
  const int bb = L >> mnShift;
  const int r  = L & ((1 << mnShift) - 1);
  const int m0 = (r >> 2) * 256;
  const int n0 = (r & 3) * 256;

  const int tid  = threadIdx.x;
  const int lane = tid & 63;
  const int w    = tid >> 6;          // 8 waves: 2(M) x 4(N)
  const int wr   = (w >> 2) * 128;
  const int wc   = (w & 3) * 64;
  const int l15  = lane & 15;
  const int g0   = lane >> 4;

  const int srow = tid >> 2;
  const int scol = ((tid & 3) ^ ((srow >> 1) & 3)) * 8;
  const unsigned short* sp[4];
  {
    const size_t aOff = (size_t)bb * aBatch + (size_t)(m0 + srow) * 1024 + scol;
    const size_t bOff = (size_t)bb * bBatch + (size_t)(n0 + srow) * 1024 + scol;
    sp[0] = Ahi + aOff; sp[1] = Alo + aOff;
    sp[2] = Bhi + bOff; sp[3] = Blo + bOff;
  }

  auto stage_half = [&](int buf, int h, int kt) {
    #pragma unroll
    for (int op = 0; op < 4; ++op) {
      const unsigned short* g = sp[op] + (size_t)h * (128 * 1024) + kt * 32;
      unsigned short* l = lds + buf * 32768 + op * 8192 + h * 4096 + tid * 8;
      __builtin_amdgcn_global_load_lds((const __attribute__((address_space(1))) void*)g,
                                       (__attribute__((address_space(3))) void*)l, 16, 0, 0);
    }
  };

  f32x4 acc[8][4];
  const f32x4 vzero = {0.f, 0.f, 0.f, 0.f};
  #pragma unroll
  for (int f = 0; f < 8; ++f)
    #pragma unroll
    for (int j = 0; j < 4; ++j) acc[f][j] = vzero;

  short8 ah[4], al[4], bh0[2], bl0[2], bh1[2], bl1[2];

  stage_half(0, 0, 0);
  stage_half(0, 1, 0);
  stage_half(1, 0, 1);
  asm volatile("s_waitcnt vmcnt(4)" ::: "memory");
  __builtin_amdgcn_s_barrier();

  #pragma unroll 1
  for (int t = 0; t < NT; ++t) {
    const int c = t & 1;
    const unsigned short* tb = lds + c * 32768;

    // ======== q0: frags {f0-3 x j0-1}; stage h1 of t+1 ========
    #pragma unroll
    for (int f = 0; f < 4; ++f) {
      ah[f] = fragr32(tb,        wr + f * 16 + l15, g0);
      al[f] = fragr32(tb + 8192, wr + f * 16 + l15, g0);
    }
    #pragma unroll
    for (int j = 0; j < 2; ++j) {
      bh0[j] = fragr32(tb + 16384, wc + j * 16 + l15, g0);
      bl0[j] = fragr32(tb + 24576, wc + j * 16 + l15, g0);
    }
    if (t + 1 < NT) stage_half(c ^ 1, 1, t + 1);
    __builtin_amdgcn_s_barrier();
    asm volatile("s_waitcnt lgkmcnt(0)" ::: "memory");
    __builtin_amdgcn_sched_barrier(0);
    __builtin_amdgcn_s_setprio(1);
    // 3 passes of 8 independent MFMAs (break same-acc dependency chains)
    #pragma unroll
    for (int f = 0; f < 4; ++f)
      #pragma unroll
      for (int j = 0; j < 2; ++j) MFMA1(acc[f][j], ah[f], bh0[j]);
    #pragma unroll
    for (int f = 0; f < 4; ++f)
      #pragma unroll
      for (int j = 0; j < 2; ++j) MFMA1(acc[f][j], ah[f], bl0[j]);
    #pragma unroll
    for (int f = 0; f < 4; ++f)
      #pragma unroll
      for (int j = 0; j < 2; ++j) MFMA1(acc[f][j], al[f], bh0[j]);
    __builtin_amdgcn_s_setprio(0);
    __builtin_amdgcn_s_barrier();

    // ======== q1: frags {f0-3 x j2-3} ========
    #pragma unroll
    for (int j = 0; j < 2; ++j) {
      bh1[j] = fragr32(tb + 16384, wc + (j + 2) * 16 + l15, g0);
      bl1[j] = fragr32(tb + 24576, wc + (j + 2) * 16 + l15, g0);
    }
    __builtin_amdgcn_s_barrier();
    asm volatile("s_waitcnt lgkmcnt(0)" ::: "memory");
    __builtin_amdgcn_sched_barrier(0);
    __builtin_amdgcn_s_setprio(1);
    #pragma unroll
    for (int f = 0; f < 4; ++f)
      #pragma unroll
      for (int j = 0; j < 2; ++j) MFMA1(acc[f][j + 2], ah[f], bh1[j]);
    #pragma unroll
    for (int f = 0; f < 4; ++f)
      #pragma unroll
      for (int j = 0; j < 2; ++j) MFMA1(acc[f][j + 2], ah[f], bl1[j]);
    #pragma unroll
    for (int f = 0; f < 4; ++f)
      #pragma unroll
      for (int j = 0; j < 2; ++j) MFMA1(acc[f][j + 2], al[f], bh1[j]);
    __builtin_amdgcn_s_setprio(0);
    __builtin_amdgcn_s_barrier();

    // ======== q2: frags {f4-7 x j0-1} ========
    #pragma unroll
    for (int f = 0; f < 4; ++f) {
      ah[f] = fragr32(tb,        wr + 64 + f * 16 + l15, g0);
      al[f] = fragr32(tb + 8192, wr + 64 + f * 16 + l15, g0);
    }
    __builtin_amdgcn_s_barrier();
    asm volatile("s_waitcnt lgkmcnt(0)" ::: "memory");
    __builtin_amdgcn_sched_barrier(0);
    __builtin_amdgcn_s_setprio(1);
    #pragma unroll
    for (int f = 0; f < 4; ++f)
      #pragma unroll
      for (int j = 0; j < 2; ++j) MFMA1(acc[4 + f][j], ah[f], bh0[j]);
    #pragma unroll
    for (int f = 0; f < 4; ++f)
      #pragma unroll
      for (int j = 0; j < 2; ++j) MFMA1(acc[4 + f][j], ah[f], bl0[j]);
    #pragma unroll
    for (int f = 0; f < 4; ++f)
      #pragma unroll
      for (int j = 0; j < 2; ++j) MFMA1(acc[4 + f][j], al[f], bh0[j]);
    __builtin_amdgcn_s_setprio(0);
    __builtin_amdgcn_s_barrier();

    // ======== q3: frags {f4-7 x j2-3}; stage h0 of t+2; counted vmcnt ========
    if (t + 2 < NT) stage_half(c, 0, t + 2);
    __builtin_amdgcn_s_barrier();
    __builtin_amdgcn_sched_barrier(0);
    __builtin_amdgcn_s_setprio(1);
    #pragma unroll
    for (int f = 0; f < 4; ++f)
      #pragma unroll
      for (int j = 0; j < 2; ++j) MFMA1(acc[4 + f][j + 2], ah[f], bh1[j]);
    #pragma unroll
    for (int f = 0; f < 4; ++f)
      #pragma unroll
      for (int j = 0; j < 2; ++j) MFMA1(acc[4 + f][j + 2], ah[f], bl1[j]);
    #pragma unroll
    for (int f = 0; f < 4; ++f)
      #pragma unroll
      for (int j = 0; j < 2; ++j) MFMA1(acc[4 + f][j + 2], al[f], bh1[j]);
    __builtin_amdgcn_s_setprio(0);
    if (t + 2 < NT) asm volatile("s_waitcnt vmcnt(4)" ::: "memory");
    else            asm volatile("s_waitcnt vmcnt(0)" ::: "memory");
    __builtin_amdgcn_s_barrier();
  }

  // ---- epilogue: C/D layout col=lane&15, row=(lane>>4)*4+q ----
  const int lr = (lane >> 4) * 4;
  const int lc = lane & 15;
  #pragma unroll
  for (int f = 0; f < 8; ++f)
    #pragma unroll
    for (int j = 0; j < 4; ++j)
      #pragma unroll
      for (int q = 0; q < 4; ++q) {
        int rr = m0 + wr + f * 16 + lr + q;
        int cc = n0 + wc + j * 16 + lc;
        float v = acc[f][j][q];
        if constexpr (MODE == 0) {
          unsigned short h = f2bfu(v);
          unsigned short l = f2bfu(v - bfu2f(h));
          outHi[(size_t)rr * 1024 + cc] = h;
          outLo[(size_t)rr * 1024 + cc] = l;
        } else {
          outF[((size_t)rr * 16 + bb) * 1024 + cc] = v;
        }
      }
}

// ---------- plain bf16 GEMM (K4): 256x128 tile, BK=32, 3-buffer ring, 2 blocks/CU ----------
// C[m,n] = sum_k P[m,k]*V[n,k]; out f32 at (rr*16+b)*1024+cc
__global__ void __launch_bounds__(512, 4)
gemm_pv(const unsigned short* __restrict__ P, const unsigned short* __restrict__ V,
        float* __restrict__ outF) {
  constexpr int NT = 32;
  __shared__ __align__(16) unsigned short lds[3 * 12288];  // 72 KiB ring {A 16K, B 8K bytes}

  const int hw = blockIdx.x;                 // 512 blocks
  const int L  = (hw & 7) * 64 + (hw >> 3);  // XCD-chunked, bijective (512 = 8*64)
  const int bb = L >> 5;                     // 16 batches
  const int r  = L & 31;
  const int m0 = (r >> 3) * 256;             // 4 M-tiles over T
  const int n0 = (r & 7) * 128;              // 8 N-tiles over D

  const int tid  = threadIdx.x;
  const int lane = tid & 63;
  const int w    = tid >> 6;         // 8 waves: 2(M) x 4(N)
  const int wrA  = (w >> 2) * 128;
  const int wcB  = (w & 3) * 32;
  const int l15  = lane & 15;
  const int g0   = lane >> 4;

  const int srow = tid >> 2;                               // 0..127
  const int scol = ((tid & 3) ^ ((srow >> 1) & 3)) * 8;
  const unsigned short* gA = P + (size_t)bb * (Tdim * Sdim) + (size_t)(m0 + srow) * 1024 + scol;
  const unsigned short* gB = V + (size_t)bb * (Ddim * Sdim) + (size_t)(n0 + srow) * 1024 + scol;

  auto stage = [&](int buf, int kt) {
    unsigned short* lb = lds + buf * 12288;
    #pragma unroll
    for (int h = 0; h < 2; ++h) {
      const unsigned short* g = gA + (size_t)h * (128 * 1024) + kt * 32;
      __builtin_amdgcn_global_load_lds((const __attribute__((address_space(1))) void*)g,
                                       (__attribute__((address_space(3))) void*)(lb + h * 4096 + tid * 8),
                                       16, 0, 0);
    }
    __builtin_amdgcn_global_load_lds((const __attribute__((address_space(1))) void*)(gB + kt * 32),
                                     (__attribute__((address_space(3))) void*)(lb + 8192 + tid * 8),
                                     16, 0, 0);
  };

  f32x4 acc[8][2];
  const f32x4 vzero = {0.f, 0.f, 0.f, 0.f};
  #pragma unroll
  for (int f = 0; f < 8; ++f) { acc[f][0] = vzero; acc[f][1] = vzero; }

  stage(0, 0);
  stage(1, 1);

  #pragma unroll 1
  for (int t = 0; t < NT; ++t) {
    const unsigned short* tb = lds + (t % 3) * 12288;
    if (t + 2 < NT) {
      stage((t + 2) % 3, t + 2);
      asm volatile("s_waitcnt vmcnt(3)" ::: "memory");
    } else {
      asm volatile("s_waitcnt vmcnt(0)" ::: "memory");
    }
    __builtin_amdgcn_s_barrier();

    short8 af[4], bf_[2];
    #pragma unroll
    for (int j = 0; j < 2; ++j) bf_[j] = fragr32(tb + 8192, wcB + j * 16 + l15, g0);
    #pragma unroll
    for (int f = 0; f < 4; ++f) af[f] = fragr32(tb, wrA + f * 16 + l15, g0);
    asm volatile("s_waitcnt lgkmcnt(0)" ::: "memory");
    __builtin_amdgcn_sched_barrier(0);
    __builtin_amdgcn_s_setprio(1);
    #pragma unroll
    for (int f = 0; f < 4; ++f)
      #pragma unroll
      for (int j = 0; j < 2; ++j) MFMA1(acc[f][j], af[f], bf_[j]);
    __builtin_amdgcn_s_setprio(0);
    #pragma unroll
    for (int f = 0; f < 4; ++f) af[f] = fragr32(tb, wrA + 64 + f * 16 + l15, g0);
    asm volatile("s_waitcnt lgkmcnt(0)" ::: "memory");
    __builtin_amdgcn_sched_barrier(0);
    __builtin_amdgcn_s_setprio(1);
    #pragma unroll
    for (int f = 0; f < 4; ++f)
      #pragma unroll
      for (int j = 0; j < 2; ++j) MFMA1(acc[4 + f][j], af[f], bf_[j]);
    __builtin_amdgcn_s_setprio(0);
    __builtin_amdgcn_s_barrier();
  }

  const int lr = (lane >> 4) * 4;
  const int lc = lane & 15;
  #pragma unroll
  for (int f = 0; f < 8; ++f)
    #pragma unroll
    for (int j = 0; j < 2; ++j)
      #pragma unroll
      for (int q = 0; q < 4; ++q) {
        int rr = m0 + wrA + f * 16 + lr + q;
        int cc = n0 + wcB + j * 16 + lc;
        outF[((size_t)rr * 16 + bb) * 1024 + cc] = acc[f][j][q];
      }
}

// ---------- in-place row softmax on [T,B,S] fp32 + bf16 copy to p[B,T,S] ----------
__global__ void __launch_bounds__(256)
softmax_kernel(float* __restrict__ av, unsigned short* __restrict__ p) {
  int row = blockIdx.x;           // row = t*16 + b
  int t = row >> 4, b = row & 15;
  float* a = av + (size_t)row * 1024;
  int tid = threadIdx.x, lane = tid & 63, wid = tid >> 6;
  float4 v = reinterpret_cast<float4*>(a)[tid];
  float mx = fmaxf(fmaxf(v.x, v.y), fmaxf(v.z, v.w));
  #pragma unroll
  for (int o = 1; o < 64; o <<= 1) mx = fmaxf(mx, __shfl_xor(mx, o));
  __shared__ float redM[4], redS[4];
  if (lane == 0) redM[wid] = mx;
  __syncthreads();
  mx = fmaxf(fmaxf(redM[0], redM[1]), fmaxf(redM[2], redM[3]));
  float e0 = __expf(v.x - mx), e1 = __expf(v.y - mx);
  float e2 = __expf(v.z - mx), e3 = __expf(v.w - mx);
  float s = (e0 + e1) + (e2 + e3);
  #pragma unroll
  for (int o = 1; o < 64; o <<= 1) s += __shfl_xor(s, o);
  if (lane == 0) redS[wid] = s;
  __syncthreads();
  s = (redS[0] + redS[1]) + (redS[2] + redS[3]);
  float inv = 1.0f / s;
  float4 o4;
  o4.x = e0 * inv; o4.y = e1 * inv; o4.z = e2 * inv; o4.w = e3 * inv;
  reinterpret_cast<float4*>(a)[tid] = o4;
  ushort4 pb;
  pb.x = f2bfu(o4.x); pb.y = f2bfu(o4.y); pb.z = f2bfu(o4.z); pb.w = f2bfu(o4.w);
  reinterpret_cast<ushort4*>(p + ((size_t)b * Tdim + t) * Sdim)[tid] = pb;
}

extern "C" void kernel_launch(void* const* d_in, const int* in_sizes, int n_in,
                              void* d_out, int out_size, void* d_ws, size_t ws_size,
                              hipStream_t stream) {
  const float* input = (const float*)d_in[0];  // [B,T,D]
  const float* ctx   = (const float*)d_in[1];  // [B,S,D]
  const float* Wt    = (const float*)d_in[2];  // [D,D]
  float* attn_out  = (float*)d_out;                               // [T,B,D]
  float* align_out = attn_out + (size_t)Tdim * Bdim * Ddim;       // [T,B,S]

  const size_t NE = (size_t)Bdim * Tdim * Ddim;  // 16M elems
  unsigned short* A0  = (unsigned short*)d_ws;
  unsigned short* A1  = A0 + NE;
  unsigned short* Whi = A1 + NE;
  unsigned short* Wlo = Whi + (size_t)Ddim * Ddim;
  unsigned short* C0  = Wlo + (size_t)Ddim * Ddim;
  unsigned short* C1  = C0 + NE;

  // split input and W
  split_kernel<<<2048, 256, 0, stream>>>(input, A0, A1, (int)(NE / 4));
  split_kernel<<<512, 256, 0, stream>>>(Wt, Whi, Wlo, (int)((size_t)Ddim * Ddim / 4));
  // K1: h = x @ W^T (split), M = 16384 -> 64x4 tiles, mnShift=8
  gemm8<0><<<256, 512, 0, stream>>>(
      A0, A1, Whi, Wlo, 0, 0, 8, C0, C1, nullptr);
  // split ctx (reuse A region)
  split_kernel<<<2048, 256, 0, stream>>>(ctx, A0, A1, (int)(NE / 4));
  // K2: align = h @ ctx^T (split), 16 batches x 4x4 tiles, mnShift=4
  gemm8<1><<<256, 512, 0, stream>>>(
      C0, C1, A0, A1, (size_t)Tdim * Ddim, (size_t)Sdim * Ddim, 4, nullptr, nullptr, align_out);
  // K3: in-place softmax; also emit p bf16 [B,T,S] into C0
  softmax_kernel<<<Bdim * Tdim, 256, 0, stream>>>(align_out, C0);
  // ctxT bf16 [B,D,S] into C1
  transpose_ctx_kernel<<<dim3(16, 16, Bdim), 256, 0, stream>>>(ctx, C1);
  // K4: attn = p @ ctx (plain bf16, dedicated 2-blocks/CU kernel), out [T,B,D]
  gemm_pv<<<512, 512, 0, stream>>>(C0, C1, attn_out);
}

// Round 5
// 251.931 us; speedup vs baseline: 1.5621x; 1.2137x over previous
//
#include <hip/hip_runtime.h>
#include <hip/hip_bf16.h>

using short8 = __attribute__((ext_vector_type(8))) short;
using half8  = __attribute__((ext_vector_type(8))) _Float16;
using f32x4  = __attribute__((ext_vector_type(4))) float;

constexpr int Bdim = 16;
constexpr int Tdim = 1024;
constexpr int Sdim = 1024;
constexpr int Ddim = 1024;

__device__ __forceinline__ unsigned short f2hu(float x) {
  _Float16 h = (_Float16)x;
  return __builtin_bit_cast(unsigned short, h);
}
__device__ __forceinline__ float hu2f(unsigned short u) {
  return (float)__builtin_bit_cast(_Float16, u);
}

// ---------- split fp32 -> fp16 (hi, lo) ----------
__global__ void __launch_bounds__(256)
split2_kernel(const float* __restrict__ src, unsigned short* __restrict__ hi,
              unsigned short* __restrict__ lo, int n4) {
  int i = blockIdx.x * blockDim.x + threadIdx.x;
  int stride = gridDim.x * blockDim.x;
  for (; i < n4; i += stride) {
    float4 v = reinterpret_cast<const float4*>(src)[i];
    ushort4 h, l;
    h.x = f2hu(v.x); l.x = f2hu(v.x - hu2f(h.x));
    h.y = f2hu(v.y); l.y = f2hu(v.y - hu2f(h.y));
    h.z = f2hu(v.z); l.z = f2hu(v.z - hu2f(h.z));
    h.w = f2hu(v.w); l.w = f2hu(v.w - hu2f(h.w));
    reinterpret_cast<ushort4*>(hi)[i] = h;
    reinterpret_cast<ushort4*>(lo)[i] = l;
  }
}

// ---------- fp32 -> fp16 single ----------
__global__ void __launch_bounds__(256)
conv_kernel(const float* __restrict__ src, unsigned short* __restrict__ dst, int n4) {
  int i = blockIdx.x * blockDim.x + threadIdx.x;
  int stride = gridDim.x * blockDim.x;
  for (; i < n4; i += stride) {
    float4 v = reinterpret_cast<const float4*>(src)[i];
    ushort4 h;
    h.x = f2hu(v.x); h.y = f2hu(v.y); h.z = f2hu(v.z); h.w = f2hu(v.w);
    reinterpret_cast<ushort4*>(dst)[i] = h;
  }
}

// ---------- ctx [B,S,D] fp32 -> ctx16 [B,S,D] fp16 AND ctxT [B,D,S] fp16 ----------
__global__ void __launch_bounds__(256)
ctxprep_kernel(const float* __restrict__ ctx, unsigned short* __restrict__ ctx16,
               unsigned short* __restrict__ ctxT) {
  __shared__ float tile[64][65];
  int b = blockIdx.z;
  int d0 = blockIdx.x * 64, s0 = blockIdx.y * 64;
  const float* src = ctx + (size_t)b * Sdim * Ddim;
  unsigned short* dstS = ctx16 + (size_t)b * Sdim * Ddim;
  unsigned short* dstT = ctxT + (size_t)b * Ddim * Sdim;
  int tx = threadIdx.x & 15, ty = threadIdx.x >> 4;
  #pragma unroll
  for (int r = 0; r < 4; ++r) {
    int s = ty + r * 16;
    float4 v = reinterpret_cast<const float4*>(src + (size_t)(s0 + s) * Ddim + d0)[tx];
    ushort4 hs;
    hs.x = f2hu(v.x); hs.y = f2hu(v.y); hs.z = f2hu(v.z); hs.w = f2hu(v.w);
    reinterpret_cast<ushort4*>(dstS + (size_t)(s0 + s) * Ddim + d0)[tx] = hs;
    tile[s][tx * 4 + 0] = v.x; tile[s][tx * 4 + 1] = v.y;
    tile[s][tx * 4 + 2] = v.z; tile[s][tx * 4 + 3] = v.w;
  }
  __syncthreads();
  #pragma unroll
  for (int r = 0; r < 4; ++r) {
    int d = ty + r * 16;
    ushort4 o;
    o.x = f2hu(tile[tx * 4 + 0][d]);
    o.y = f2hu(tile[tx * 4 + 1][d]);
    o.z = f2hu(tile[tx * 4 + 2][d]);
    o.w = f2hu(tile[tx * 4 + 3][d]);
    reinterpret_cast<ushort4*>(dstT + (size_t)(d0 + d) * Sdim + s0)[tx] = o;
  }
}

// LDS frag read, 64B rows, XOR swizzle (verified 0 bank conflicts r1-r4)
__device__ __forceinline__ short8 fragr(const unsigned short* t, int row, int g0) {
  int pg = g0 ^ ((row >> 1) & 3);
  return *reinterpret_cast<const short8*>(t + row * 32 + pg * 8);
}

#define MFMAH(d, x, y)                                                          \
  d = __builtin_amdgcn_mfma_f32_16x16x32_f16(__builtin_bit_cast(half8, (x)),    \
                                             __builtin_bit_cast(half8, (y)), (d), 0, 0, 0)

// ---------- unified 256x256-tile 8-wave GEMM, ring-3 tile buffers, depth-2 vmcnt ----------
// C[m,n] = sum_k A[m,k]*B[n,k], K=1024 (B^T form), fp16 operands.
// TERMS=2: A split (Ah+Al), B single -> 2 MFMA/term-pair. TERMS=1: plain.
// MODE 0: out fp16 hi/lo at rr*1024+cc ; MODE 1: out f32 at (rr*16+bb)*1024+cc
template <int TERMS, int MODE>
__global__ void __launch_bounds__(512, 2)
gemmU(const unsigned short* __restrict__ Ah, const unsigned short* __restrict__ Al,
      const unsigned short* __restrict__ Bh,
      size_t aBatch, size_t bBatch, int mnShift,
      unsigned short* __restrict__ outHi, unsigned short* __restrict__ outLo,
      float* __restrict__ outF) {
  constexpr int OPS = TERMS + 1;
  constexpr int BUFSTRIDE = OPS * 8192;     // ushorts per ring buffer
  constexpr int NT = 32;
  __shared__ __align__(16) unsigned short lds[3 * BUFSTRIDE];  // 144 / 96 KiB

  // XCD-chunked bijective swizzle (256 blocks): kept — cut FETCH 5x in r3/r4
  const int hw = blockIdx.x;
  const int L  = (hw & 7) * 32 + (hw >> 3);
  const int bb = L >> mnShift;
  const int r  = L & ((1 << mnShift) - 1);
  const int m0 = (r >> 2) * 256;
  const int n0 = (r & 3) * 256;

  const int tid  = threadIdx.x;
  const int lane = tid & 63;
  const int w    = tid >> 6;          // 8 waves: 2(M) x 4(N)
  const int wr   = (w >> 2) * 128;
  const int wc   = (w & 3) * 64;
  const int l15  = lane & 15;
  const int g0   = lane >> 4;

  // staging: pre-swizzled global source col (m173), linear LDS dest
  const int srow = tid >> 2;                               // 0..127
  const int scol = ((tid & 3) ^ ((srow >> 1) & 3)) * 8;
  const unsigned short* sp[OPS];
  {
    const size_t aOff = (size_t)bb * aBatch + (size_t)(m0 + srow) * 1024 + scol;
    const size_t bOff = (size_t)bb * bBatch + (size_t)(n0 + srow) * 1024 + scol;
    sp[0] = Ah + aOff;
    if constexpr (TERMS == 2) sp[1] = Al + aOff;
    sp[OPS - 1] = Bh + bOff;
  }

  // stage full tile kt into ring buffer buf: OPS*2 gload_lds instrs/thread
  auto stage_tile = [&](int buf, int kt) {
    #pragma unroll
    for (int op = 0; op < OPS; ++op)
      #pragma unroll
      for (int h = 0; h < 2; ++h) {
        const unsigned short* g = sp[op] + (size_t)h * (128 * 1024) + kt * 32;
        unsigned short* l = lds + buf * BUFSTRIDE + op * 8192 + h * 4096 + tid * 8;
        __builtin_amdgcn_global_load_lds((const __attribute__((address_space(1))) void*)g,
                                         (__attribute__((address_space(3))) void*)l, 16, 0, 0);
      }
  };

  f32x4 acc[8][4];
  const f32x4 vzero = {0.f, 0.f, 0.f, 0.f};
  #pragma unroll
  for (int f = 0; f < 8; ++f)
    #pragma unroll
    for (int j = 0; j < 4; ++j) acc[f][j] = vzero;

  short8 ah[4], al[4], b0[2], b1[2];

  stage_tile(0, 0);
  stage_tile(1, 1);

  #pragma unroll 1
  for (int t = 0; t < NT; ++t) {
    const unsigned short* tb = lds + (t % 3) * BUFSTRIDE;
    const unsigned short* tA = tb;
    const unsigned short* tAl = tb + 8192;
    const unsigned short* tB = tb + (OPS - 1) * 8192;

    // stage t+2 (tail: benign re-stage of last tile keeps vmcnt topology uniform)
    stage_tile((t + 2) % 3, (t + 2 < NT) ? (t + 2) : (NT - 1));
    // wait for tile t only: leave {t+1, t+2} = 2*OPS*2 loads in flight
    if constexpr (TERMS == 2) asm volatile("s_waitcnt vmcnt(12)" ::: "memory");
    else                      asm volatile("s_waitcnt vmcnt(8)" ::: "memory");
    __builtin_amdgcn_s_barrier();
    asm volatile("" ::: "memory");

    // q0: {f0-3 x j0-1}
    #pragma unroll
    for (int f = 0; f < 4; ++f) {
      ah[f] = fragr(tA, wr + f * 16 + l15, g0);
      if constexpr (TERMS == 2) al[f] = fragr(tAl, wr + f * 16 + l15, g0);
    }
    #pragma unroll
    for (int j = 0; j < 2; ++j) b0[j] = fragr(tB, wc + j * 16 + l15, g0);
    __builtin_amdgcn_s_setprio(1);
    #pragma unroll
    for (int f = 0; f < 4; ++f)
      #pragma unroll
      for (int j = 0; j < 2; ++j) {
        MFMAH(acc[f][j], ah[f], b0[j]);
        if constexpr (TERMS == 2) MFMAH(acc[f][j], al[f], b0[j]);
      }
    __builtin_amdgcn_s_setprio(0);

    // q1: {f0-3 x j2-3}
    #pragma unroll
    for (int j = 0; j < 2; ++j) b1[j] = fragr(tB, wc + (j + 2) * 16 + l15, g0);
    __builtin_amdgcn_s_setprio(1);
    #pragma unroll
    for (int f = 0; f < 4; ++f)
      #pragma unroll
      for (int j = 0; j < 2; ++j) {
        MFMAH(acc[f][j + 2], ah[f], b1[j]);
        if constexpr (TERMS == 2) MFMAH(acc[f][j + 2], al[f], b1[j]);
      }
    __builtin_amdgcn_s_setprio(0);

    // q2: {f4-7 x j0-1}
    #pragma unroll
    for (int f = 0; f < 4; ++f) {
      ah[f] = fragr(tA, wr + 64 + f * 16 + l15, g0);
      if constexpr (TERMS == 2) al[f] = fragr(tAl, wr + 64 + f * 16 + l15, g0);
    }
    __builtin_amdgcn_s_setprio(1);
    #pragma unroll
    for (int f = 0; f < 4; ++f)
      #pragma unroll
      for (int j = 0; j < 2; ++j) {
        MFMAH(acc[4 + f][j], ah[f], b0[j]);
        if constexpr (TERMS == 2) MFMAH(acc[4 + f][j], al[f], b0[j]);
      }
    __builtin_amdgcn_s_setprio(0);

    // q3: {f4-7 x j2-3}
    __builtin_amdgcn_s_setprio(1);
    #pragma unroll
    for (int f = 0; f < 4; ++f)
      #pragma unroll
      for (int j = 0; j < 2; ++j) {
        MFMAH(acc[4 + f][j + 2], ah[f], b1[j]);
        if constexpr (TERMS == 2) MFMAH(acc[4 + f][j + 2], al[f], b1[j]);
      }
    __builtin_amdgcn_s_setprio(0);
    asm volatile("" ::: "memory");
    __builtin_amdgcn_s_barrier();
  }

  // epilogue: C/D layout col=lane&15, row=(lane>>4)*4+q (m89/m91 verified)
  const int lr = (lane >> 4) * 4;
  const int lc = lane & 15;
  #pragma unroll
  for (int f = 0; f < 8; ++f)
    #pragma unroll
    for (int j = 0; j < 4; ++j)
      #pragma unroll
      for (int q = 0; q < 4; ++q) {
        int rr = m0 + wr + f * 16 + lr + q;
        int cc = n0 + wc + j * 16 + lc;
        float v = acc[f][j][q];
        if constexpr (MODE == 0) {
          unsigned short h = f2hu(v);
          unsigned short l = f2hu(v - hu2f(h));
          outHi[(size_t)rr * 1024 + cc] = h;
          outLo[(size_t)rr * 1024 + cc] = l;
        } else {
          outF[((size_t)rr * 16 + bb) * 1024 + cc] = v;
        }
      }
}

// ---------- in-place row softmax on [T,B,S] fp32 + fp16 copy to p[B,T,S] ----------
__global__ void __launch_bounds__(256)
softmax_kernel(float* __restrict__ av, unsigned short* __restrict__ p) {
  int row = blockIdx.x;           // row = t*16 + b
  int t = row >> 4, b = row & 15;
  float* a = av + (size_t)row * 1024;
  int tid = threadIdx.x, lane = tid & 63, wid = tid >> 6;
  float4 v = reinterpret_cast<float4*>(a)[tid];
  float mx = fmaxf(fmaxf(v.x, v.y), fmaxf(v.z, v.w));
  #pragma unroll
  for (int o = 1; o < 64; o <<= 1) mx = fmaxf(mx, __shfl_xor(mx, o));
  __shared__ float redM[4], redS[4];
  if (lane == 0) redM[wid] = mx;
  __syncthreads();
  mx = fmaxf(fmaxf(redM[0], redM[1]), fmaxf(redM[2], redM[3]));
  float e0 = __expf(v.x - mx), e1 = __expf(v.y - mx);
  float e2 = __expf(v.z - mx), e3 = __expf(v.w - mx);
  float s = (e0 + e1) + (e2 + e3);
  #pragma unroll
  for (int o = 1; o < 64; o <<= 1) s += __shfl_xor(s, o);
  if (lane == 0) redS[wid] = s;
  __syncthreads();
  s = (redS[0] + redS[1]) + (redS[2] + redS[3]);
  float inv = 1.0f / s;
  float4 o4;
  o4.x = e0 * inv; o4.y = e1 * inv; o4.z = e2 * inv; o4.w = e3 * inv;
  reinterpret_cast<float4*>(a)[tid] = o4;
  ushort4 pb;
  pb.x = f2hu(o4.x); pb.y = f2hu(o4.y); pb.z = f2hu(o4.z); pb.w = f2hu(o4.w);
  reinterpret_cast<ushort4*>(p + ((size_t)b * Tdim + t) * Sdim)[tid] = pb;
}

extern "C" void kernel_launch(void* const* d_in, const int* in_sizes, int n_in,
                              void* d_out, int out_size, void* d_ws, size_t ws_size,
                              hipStream_t stream) {
  const float* input = (const float*)d_in[0];  // [B,T,D]
  const float* ctx   = (const float*)d_in[1];  // [B,S,D]
  const float* Wt    = (const float*)d_in[2];  // [D,D]
  float* attn_out  = (float*)d_out;                               // [T,B,D]
  float* align_out = attn_out + (size_t)Tdim * Bdim * Ddim;       // [T,B,S]

  const size_t NE = (size_t)Bdim * Tdim * Ddim;  // 16M elems
  // ws regions (130 MB): xh, xl (reused as ctx16, ctxT), Wh, hh (reused as p), hl
  unsigned short* xh = (unsigned short*)d_ws;
  unsigned short* xl = xh + NE;
  unsigned short* Wh = xl + NE;
  unsigned short* hh = Wh + (size_t)Ddim * Ddim;
  unsigned short* hl = hh + NE;
  unsigned short* ctx16 = xh;   // after K1, x dead
  unsigned short* ctxT  = xl;
  unsigned short* p     = hh;   // after K2, h dead

  split2_kernel<<<2048, 256, 0, stream>>>(input, xh, xl, (int)(NE / 4));
  conv_kernel<<<512, 256, 0, stream>>>(Wt, Wh, (int)((size_t)Ddim * Ddim / 4));
  // K1: h = x @ W^T, A=x split, B=W single; out fp16 hi/lo
  gemmU<2, 0><<<256, 512, 0, stream>>>(xh, xl, Wh, 0, 0, 8, hh, hl, nullptr);
  // ctx16 [B,S,D] + ctxT [B,D,S] fp16 (into dead x regions)
  ctxprep_kernel<<<dim3(16, 16, Bdim), 256, 0, stream>>>(ctx, ctx16, ctxT);
  // K2: align = h @ ctx^T, A=h split, B=ctx single; out f32 [T,B,S]
  gemmU<2, 1><<<256, 512, 0, stream>>>(hh, hl, ctx16, (size_t)Tdim * Ddim,
                                       (size_t)Sdim * Ddim, 4, nullptr, nullptr, align_out);
  // softmax in-place + p fp16 [B,T,S]
  softmax_kernel<<<Bdim * Tdim, 256, 0, stream>>>(align_out, p);
  // K4: attn = p @ ctx, plain fp16; out f32 [T,B,D]
  gemmU<1, 1><<<256, 512, 0, stream>>>(p, nullptr, ctxT, (size_t)Tdim * Sdim,
                                       (size_t)Ddim * Sdim, 4, nullptr, nullptr, attn_out);
}